// Round 20
// baseline (267.445 us; speedup 1.0000x reference)
//
#include <hip/hip_runtime.h>
#include <stdint.h>

typedef float f32x4 __attribute__((ext_vector_type(4)));
typedef float f32x16 __attribute__((ext_vector_type(16)));
typedef __bf16 bf16x8 __attribute__((ext_vector_type(8)));
typedef unsigned short ushort8 __attribute__((ext_vector_type(8)));
typedef unsigned int uint4v __attribute__((ext_vector_type(4)));
typedef unsigned short u16;

#define DEVINL static __device__ __forceinline__

#define EXP2(x) exp2f(x)

// counted vmcnt wait (N = loads allowed to stay in flight), order-pinned
#define VMCNT(N)                                          \
  {                                                       \
    asm volatile("s_waitcnt vmcnt(" #N ")" ::: "memory"); \
    __builtin_amdgcn_sched_barrier(0);                    \
  }

// raw workgroup barrier WITHOUT the __syncthreads vmcnt(0) drain
DEVINL void barrier_raw() {
  __builtin_amdgcn_sched_barrier(0);
  __builtin_amdgcn_s_barrier();
  __builtin_amdgcn_sched_barrier(0);
}

// fp32 -> bf16 via native convert (RNE)
DEVINL u16 f2bf(float f) {
  __bf16 h = (__bf16)f;
  return __builtin_bit_cast(u16, h);
}

// packed fp32x2 -> bf16x2 (no builtin on gfx950; inline asm per T12)
DEVINL unsigned cvtpk(float lo, float hi) {
  unsigned r;
  asm("v_cvt_pk_bf16_f32 %0, %1, %2" : "=v"(r) : "v"(lo), "v"(hi));
  return r;
}

// exchange lanes [32..63] of a with lanes [0..31] of b (VALU cross-lane)
DEVINL void plswap(unsigned& a, unsigned& b) {
  asm("v_permlane32_swap_b32 %0, %1" : "+v"(a), "+v"(b));
}

// async global->LDS, 16B per lane. LDS dest must be wave-uniform base + lane*16.
DEVINL void gload16(const void* g, void* l) {
  __builtin_amdgcn_global_load_lds((__attribute__((address_space(1))) void*)g,
                                   (__attribute__((address_space(3))) void*)l, 16, 0, 0);
}

DEVINL f32x4 mfma16(bf16x8 a, bf16x8 b, f32x4 c) {
  return __builtin_amdgcn_mfma_f32_16x16x32_bf16(a, b, c, 0, 0, 0);
}
DEVINL f32x16 mfma32(bf16x8 a, bf16x8 b, f32x16 c) {
  return __builtin_amdgcn_mfma_f32_32x32x16_bf16(a, b, c, 0, 0, 0);
}

// ---------------- fused prep: cast x -> bf16 + transpose-cast both weights --------
__global__ __launch_bounds__(256) void k_prep(const float* __restrict__ x,
                                              u16* __restrict__ xb,
                                              const float* __restrict__ Wa,
                                              u16* __restrict__ WaT,
                                              const float* __restrict__ Wp,
                                              u16* __restrict__ WpT) {
  __shared__ float tile[32][33];
  const int bid = blockIdx.x;
  if (bid < 2048) {
    const int i = bid * 256 + threadIdx.x;
    const float4* p = (const float4*)x + (size_t)i * 2;
    float4 a = p[0], b = p[1];
    ushort8 o;
    o[0] = f2bf(a.x); o[1] = f2bf(a.y); o[2] = f2bf(a.z); o[3] = f2bf(a.w);
    o[4] = f2bf(b.x); o[5] = f2bf(b.y); o[6] = f2bf(b.z); o[7] = f2bf(b.w);
    *((ushort8*)xb + i) = o;
    return;
  }
  const float* in;
  u16* out;
  int C, cx, ry;
  if (bid < 5120) {
    const int bx = bid - 2048;
    in = Wa; out = WaT; C = 3072; cx = bx % 96; ry = bx / 96;
  } else {
    const int bx = bid - 5120;
    in = Wp; out = WpT; C = 1024; cx = bx & 31; ry = bx >> 5;
  }
  const int tx = threadIdx.x & 31, ty = threadIdx.x >> 5;
  const int c0 = cx * 32, r0 = ry * 32;
#pragma unroll
  for (int k = 0; k < 4; ++k)
    tile[ty + k * 8][tx] = in[(size_t)(r0 + ty + k * 8) * C + (c0 + tx)];
  __syncthreads();
#pragma unroll
  for (int k = 0; k < 4; ++k)
    out[(size_t)(c0 + ty + k * 8) * 1024 + (r0 + tx)] = f2bf(tile[tx][ty + k * 8]);
}

// ---------------- staging: ROWS x 64 bf16 tile via global_load_lds, XOR swizzle ----
template <int ROWS>
DEVINL void stageRx64(const u16* __restrict__ g, int ld, u16* lds, int t) {
#pragma unroll
  for (int i = 0; i < ROWS / 32; ++i) {
    int ci = i * 256 + t;
    int row = ci >> 3, gr = ci & 7;
    int gs = gr ^ (row & 7);
    gload16(g + (size_t)row * ld + gs * 8, lds + ci * 8);
  }
}

// ---------------- staging: ROWS x 32 bf16 tile (BK=32), conflict-free swizzle -----
template <int ROWS>
DEVINL void stageRx32(const u16* __restrict__ g, int ld, u16* lds, int t) {
#pragma unroll
  for (int i = 0; i < ROWS / 64; ++i) {
    int ci = i * 256 + t;
    int row = ci >> 2, gr = ci & 3;
    int gs = gr ^ ((row >> 1) & 3);
    gload16(g + (size_t)row * ld + gs * 8, lds + ci * 8);
  }
}

// ---------------- GEMM core: 128x128 tile, BK=32, 32KB LDS -> 3+/CU ---------------
DEVINL void gemm_core_128b32(const u16* __restrict__ A, const u16* __restrict__ B,
                             int Kdim, u16* As, u16* Bs, int t, f32x4 acc[4][4]) {
  const int l = t & 63, lr = l & 15, lg = l >> 4;
  const int wr = t >> 7, wc = (t >> 6) & 1;
  const int nk = Kdim >> 5;  // BK=32
  stageRx32<128>(A, Kdim, As, t);
  stageRx32<128>(B, Kdim, Bs, t);
  for (int kt = 0; kt < nk; ++kt) {
    if (kt + 1 < nk) {
      stageRx32<128>(A + (kt + 1) * 32, Kdim, As + ((kt + 1) & 1) * 4096, t);
      stageRx32<128>(B + (kt + 1) * 32, Kdim, Bs + ((kt + 1) & 1) * 4096, t);
      VMCNT(4);
    } else {
      VMCNT(0);
    }
    barrier_raw();
    const u16* Asc = As + (kt & 1) * 4096;
    const u16* Bsc = Bs + (kt & 1) * 4096;
    bf16x8 af[4], bf[4];
#pragma unroll
    for (int mi = 0; mi < 4; ++mi) {
      int r = wr * 64 + mi * 16 + lr;
      int g = lg ^ ((r >> 1) & 3);
      af[mi] = *(const bf16x8*)(Asc + r * 32 + g * 8);
    }
#pragma unroll
    for (int ni = 0; ni < 4; ++ni) {
      int r = wc * 64 + ni * 16 + lr;
      int g = lg ^ ((r >> 1) & 3);
      bf[ni] = *(const bf16x8*)(Bsc + r * 32 + g * 8);
    }
#pragma unroll
    for (int mi = 0; mi < 4; ++mi)
#pragma unroll
      for (int ni = 0; ni < 4; ++ni)
        acc[mi][ni] = mfma16(af[mi], bf[ni], acc[mi][ni]);
    barrier_raw();
  }
}

// ---------------- GEMM core: 64x128 tile (proj, proven) ---------------------------
DEVINL void gemm_core_64(const u16* __restrict__ A, const u16* __restrict__ B,
                         int Kdim, u16* As, u16* Bs, int t, f32x4 acc[2][4]) {
  const int l = t & 63, lr = l & 15, lg = l >> 4;
  const int wr = t >> 7, wc = (t >> 6) & 1;
  const int nk = Kdim >> 6;
  stageRx64<64>(A, Kdim, As, t);
  stageRx64<128>(B, Kdim, Bs, t);
  for (int kt = 0; kt < nk; ++kt) {
    if (kt + 1 < nk) {
      stageRx64<64>(A + (kt + 1) * 64, Kdim, As + ((kt + 1) & 1) * 4096, t);
      stageRx64<128>(B + (kt + 1) * 64, Kdim, Bs + ((kt + 1) & 1) * 8192, t);
      VMCNT(6);
    } else {
      VMCNT(0);
    }
    barrier_raw();
    const u16* Asc = As + (kt & 1) * 4096;
    const u16* Bsc = Bs + (kt & 1) * 8192;
#pragma unroll
    for (int ks = 0; ks < 2; ++ks) {
      bf16x8 af[2], bf[4];
#pragma unroll
      for (int mi = 0; mi < 2; ++mi) {
        int r = wr * 32 + mi * 16 + lr;
        int g = (ks * 4 + lg) ^ (r & 7);
        af[mi] = *(const bf16x8*)(Asc + r * 64 + g * 8);
      }
#pragma unroll
      for (int ni = 0; ni < 4; ++ni) {
        int r = wc * 64 + ni * 16 + lr;
        int g = (ks * 4 + lg) ^ (r & 7);
        bf[ni] = *(const bf16x8*)(Bsc + r * 64 + g * 8);
      }
#pragma unroll
      for (int mi = 0; mi < 2; ++mi)
#pragma unroll
        for (int ni = 0; ni < 4; ++ni)
          acc[mi][ni] = mfma16(af[mi], bf[ni], acc[mi][ni]);
    }
    barrier_raw();
  }
}

// ---------------- GEMM 1: qkv = xb @ W_attn + b -> Q/K [BH][T][D], V^T [BH][D][T] --
__global__ __launch_bounds__(256) void k_gemm_qkv(const u16* __restrict__ xb,
                                                  const u16* __restrict__ WaT,
                                                  const float* __restrict__ b_attn,
                                                  u16* __restrict__ Qo,
                                                  u16* __restrict__ Ko,
                                                  u16* __restrict__ Vto) {
  __shared__ u16 As[2 * 128 * 32], Bs[2 * 128 * 32];  // 32 KB
  const int t = threadIdx.x;
  const int m0 = blockIdx.y * 128, n0 = blockIdx.x * 128;
  f32x4 acc[4][4] = {};
  gemm_core_128b32(xb + (size_t)m0 * 1024, WaT + (size_t)n0 * 1024, 1024, As, Bs, t,
                   acc);
  const int l = t & 63, lr = l & 15, lg = l >> 4;
  const int wr = t >> 7, wc = (t >> 6) & 1;
#pragma unroll
  for (int ni = 0; ni < 4; ++ni) {
    const int gcol = n0 + wc * 64 + ni * 16 + lr;
    const int part = gcol >> 10;
    const int h = (gcol & 1023) >> 6, d = gcol & 63;
    const float bias = b_attn[gcol];
    if (part == 2) {
      // V: write transposed directly -> Vt[bh][d][t]
#pragma unroll
      for (int mi = 0; mi < 4; ++mi) {
        const int tt0 = m0 + wr * 64 + mi * 16 + lg * 4;
        const int bb = tt0 >> 11, tt = tt0 & 2047;
        ushort4 pk;
        pk.x = f2bf(acc[mi][ni][0] + bias);
        pk.y = f2bf(acc[mi][ni][1] + bias);
        pk.z = f2bf(acc[mi][ni][2] + bias);
        pk.w = f2bf(acc[mi][ni][3] + bias);
        *(ushort4*)(Vto + (size_t)(bb * 16 + h) * 131072 + (size_t)d * 2048 + tt) = pk;
      }
    } else {
      const float osc = (part == 0) ? 0.18033688f : 1.0f;  // 0.125 * log2(e)
      u16* dst = (part == 0) ? Qo : Ko;
#pragma unroll
      for (int mi = 0; mi < 4; ++mi)
#pragma unroll
        for (int r = 0; r < 4; ++r) {
          const int grow = m0 + wr * 64 + mi * 16 + lg * 4 + r;
          const int bb = grow >> 11, tt = grow & 2047;
          dst[(size_t)((bb * 16 + h) * 2048 + tt) * 64 + d] =
              f2bf((acc[mi][ni][r] + bias) * osc);
        }
    }
  }
}

// ---------------- GEMM 2: out = Y @ W_proj + b (fp32 out), 64x128 tiles ----------
__global__ __launch_bounds__(256) void k_gemm_proj(const u16* __restrict__ Yb,
                                                   const u16* __restrict__ WpT,
                                                   const float* __restrict__ b_proj,
                                                   float* __restrict__ out) {
  __shared__ u16 As[2 * 64 * 64], Bs[2 * 128 * 64];  // 48 KB
  const int t = threadIdx.x;
  const int m0 = blockIdx.y * 64, n0 = blockIdx.x * 128;
  f32x4 acc[2][4] = {};
  gemm_core_64(Yb + (size_t)m0 * 1024, WpT + (size_t)n0 * 1024, 1024, As, Bs, t, acc);
  const int l = t & 63, lr = l & 15, lg = l >> 4;
  const int wr = t >> 7, wc = (t >> 6) & 1;
#pragma unroll
  for (int ni = 0; ni < 4; ++ni) {
    const int gcol = n0 + wc * 64 + ni * 16 + lr;
    const float bias = b_proj[gcol];
#pragma unroll
    for (int mi = 0; mi < 2; ++mi)
#pragma unroll
      for (int r = 0; r < 4; ++r) {
        const int grow = m0 + wr * 32 + mi * 16 + lg * 4 + r;
        out[(size_t)grow * 1024 + gcol] = acc[mi][ni][r] + bias;
      }
  }
}

// ---------------- flash attention (causal), r18 body, 2 blocks/CU ----------------
// Grid 512 single-qt blocks x 1024 thr, __launch_bounds__(1024,8) -> VGPR<=64,
// LDS 71.7KB -> 2 blocks/CU = 32 waves/CU (was 16). Complementary pairing:
// blocks bid and bid+256 get qt and 15-qt (sum 17 steps) so co-resident pairs
// balance if placement is 256-periodic; XCD map bid&7 keeps K/V L2-resident.
__global__ __launch_bounds__(1024, 8) void k_flash(const u16* __restrict__ Q,
                                                   const u16* __restrict__ K,
                                                   const u16* __restrict__ Vt,
                                                   u16* __restrict__ Y) {
  __shared__ u16 SM[2 * 9216 + 2 * 8704];  // 71,680 B
  u16* KsB = SM;                           // [2][128*72]
  u16* VsB = SM + 2 * 9216;                // [2][64*136]
  float* Ms = (float*)SM;                  // merge alias (post-loop)

  const int t = threadIdx.x, l = t & 63, w = t >> 6;
  const int ql = l & 31, hi = l >> 5;
  const int wq = w & 3, wk = w >> 2;
  const int bid = blockIdx.x;
  const int bh = (bid & 7) + 8 * ((bid >> 3) & 3);  // 4 bh per XCD
  const int jj = (bid >> 5) & 7;
  const int qt = (bid >> 8) ? (15 - jj) : jj;       // complementary pairs
  const size_t base = (size_t)bh * 131072;
  const int b = bh >> 4, hh = bh & 15;
  const int srow = t >> 3, scol = t & 7;  // K tile: 128 rows x 8 granules
  const int sd = t >> 4, sck = t & 15;    // V tile: 64 d-rows x 16 key-granules

  const int nsteps = qt + 1;  // 128-key kv tiles
  const int qbase = qt * 128 + wq * 32;
  const int qrow = qbase + ql;

  bf16x8 qb[4];
#pragma unroll
  for (int m = 0; m < 4; ++m)
    qb[m] = *(const bf16x8*)(Q + base + (size_t)qrow * 64 + hi * 8 + 16 * m);

  {
    ushort8 kv = *(const ushort8*)(K + base + (size_t)srow * 64 + scol * 8);
    ushort8 vv = *(const ushort8*)(Vt + base + (size_t)sd * 2048 + sck * 8);
    *(ushort8*)(KsB + srow * 72 + scol * 8) = kv;
    *(ushort8*)(VsB + sd * 136 + sck * 8) = vv;
  }
  __syncthreads();

  f32x16 accO0 = {}, accO1 = {};  // O^T: q=ql, d=(r&3)+8*(r>>2)+4*hi (+32)
  float rs_lane = 0.f;
  const int krow = wk * 32 + ql;

  for (int n = 0; n < nsteps; ++n) {
    const u16* Kc = KsB + (n & 1) * 9216;
    const u16* Vc = VsB + (n & 1) * 8704;
    const bool more = (n + 1 < nsteps);
    ushort8 kv, vv;
    if (more) {  // issue next-tile loads early; land under compute
      kv = *(const ushort8*)(K + base + (size_t)((n + 1) * 128 + srow) * 64 + scol * 8);
      vv = *(const ushort8*)(Vt + base + (size_t)sd * 2048 + (n + 1) * 128 + sck * 8);
    }
    const int kbase = n * 128 + wk * 32;
    if (kbase <= qbase + 31) {  // else fully masked for this wave
      f32x16 st = {};
      __builtin_amdgcn_s_setprio(1);
#pragma unroll
      for (int m = 0; m < 4; ++m) {
        bf16x8 ka = *(const bf16x8*)(Kc + krow * 72 + (hi + 2 * m) * 8);
        st = mfma32(ka, qb[m], st);
      }
      __builtin_amdgcn_s_setprio(0);
      if (kbase + 31 > qbase) {  // diagonal: causal mask
#pragma unroll
        for (int r = 0; r < 16; ++r) {
          const int keyl = (r & 3) + 8 * (r >> 2) + 4 * hi;
          if (kbase + keyl > qrow) st[r] = -1e30f;
        }
      }
      float pp[16];
#pragma unroll
      for (int r = 0; r < 16; ++r) {
        pp[r] = EXP2(st[r]);
        rs_lane += pp[r];
      }
      unsigned uu[8];
#pragma unroll
      for (int i = 0; i < 8; ++i) uu[i] = cvtpk(pp[2 * i], pp[2 * i + 1]);
      plswap(uu[0], uu[2]);
      plswap(uu[1], uu[3]);
      plswap(uu[4], uu[6]);
      plswap(uu[5], uu[7]);
      uint4v w0 = {uu[0], uu[1], uu[2], uu[3]};
      uint4v w1 = {uu[4], uu[5], uu[6], uu[7]};
      bf16x8 pf0 = __builtin_bit_cast(bf16x8, w0);
      bf16x8 pf1 = __builtin_bit_cast(bf16x8, w1);
      __builtin_amdgcn_s_setprio(1);
      {
        bf16x8 va0 = *(const bf16x8*)(Vc + ql * 136 + (4 * wk + hi) * 8);
        bf16x8 va1 = *(const bf16x8*)(Vc + ql * 136 + (4 * wk + 2 + hi) * 8);
        accO0 = mfma32(va0, pf0, accO0);
        accO0 = mfma32(va1, pf1, accO0);
        bf16x8 vb0 = *(const bf16x8*)(Vc + (32 + ql) * 136 + (4 * wk + hi) * 8);
        bf16x8 vb1 = *(const bf16x8*)(Vc + (32 + ql) * 136 + (4 * wk + 2 + hi) * 8);
        accO1 = mfma32(vb0, pf0, accO1);
        accO1 = mfma32(vb1, pf1, accO1);
      }
      __builtin_amdgcn_s_setprio(0);
    }
    if (more) {  // write next tile (compiler inserts vmcnt for kv/vv)
      u16* Kn = KsB + ((n + 1) & 1) * 9216;
      u16* Vn = VsB + ((n + 1) & 1) * 8704;
      *(ushort8*)(Kn + srow * 72 + scol * 8) = kv;
      *(ushort8*)(Vn + sd * 136 + sck * 8) = vv;
    }
    __syncthreads();  // writes visible; everyone done reading buf[n&1]
  }

  rs_lane += __shfl_xor(rs_lane, 32);

  // hierarchical 4-way wk merge (Ms aliases dead K/V buffers)
  {
    float* Mp = Ms + (size_t)(((wq * 2 + (wk >> 1)) * 64 + l)) * 33;
    if (wk & 1) {
#pragma unroll
      for (int i = 0; i < 16; ++i) Mp[i] = accO0[i];
#pragma unroll
      for (int i = 0; i < 16; ++i) Mp[16 + i] = accO1[i];
      Mp[32] = rs_lane;
    }
    __syncthreads();
    if (!(wk & 1)) {
#pragma unroll
      for (int i = 0; i < 16; ++i) accO0[i] += Mp[i];
#pragma unroll
      for (int i = 0; i < 16; ++i) accO1[i] += Mp[16 + i];
      rs_lane += Mp[32];
    }
    __syncthreads();
  }
  {
    float* Mp = Ms + (size_t)((wq * 64 + l)) * 33;
    if (wk == 2) {
#pragma unroll
      for (int i = 0; i < 16; ++i) Mp[i] = accO0[i];
#pragma unroll
      for (int i = 0; i < 16; ++i) Mp[16 + i] = accO1[i];
      Mp[32] = rs_lane;
    }
    __syncthreads();
    if (wk == 0) {
      const float inv = 1.0f / (rs_lane + Mp[32]);
      u16* yb = Y + ((size_t)(b * 2048 + qrow)) * 1024 + hh * 64;
#pragma unroll
      for (int rq = 0; rq < 4; ++rq) {
        const int d0 = 8 * rq + 4 * hi;
        ushort4 o4;
        o4.x = f2bf((accO0[rq * 4 + 0] + Mp[rq * 4 + 0]) * inv);
        o4.y = f2bf((accO0[rq * 4 + 1] + Mp[rq * 4 + 1]) * inv);
        o4.z = f2bf((accO0[rq * 4 + 2] + Mp[rq * 4 + 2]) * inv);
        o4.w = f2bf((accO0[rq * 4 + 3] + Mp[rq * 4 + 3]) * inv);
        *(ushort4*)(yb + d0) = o4;
      }
#pragma unroll
      for (int rq = 0; rq < 4; ++rq) {
        const int d0 = 32 + 8 * rq + 4 * hi;
        ushort4 o4;
        o4.x = f2bf((accO1[rq * 4 + 0] + Mp[16 + rq * 4 + 0]) * inv);
        o4.y = f2bf((accO1[rq * 4 + 1] + Mp[16 + rq * 4 + 1]) * inv);
        o4.z = f2bf((accO1[rq * 4 + 2] + Mp[16 + rq * 4 + 2]) * inv);
        o4.w = f2bf((accO1[rq * 4 + 3] + Mp[16 + rq * 4 + 3]) * inv);
        *(ushort4*)(yb + d0) = o4;
      }
    }
  }
}

// ---------------- launch ----------------
extern "C" void kernel_launch(void* const* d_in, const int* in_sizes, int n_in,
                              void* d_out, int out_size, void* d_ws, size_t ws_size,
                              hipStream_t stream) {
  const float* x      = (const float*)d_in[0];
  const float* W_attn = (const float*)d_in[1];
  const float* b_attn = (const float*)d_in[2];
  const float* W_proj = (const float*)d_in[3];
  const float* b_proj = (const float*)d_in[4];
  float* out = (float*)d_out;

  char* ws = (char*)d_ws;              // 48 MB total
  u16* xb  = (u16*)(ws);               //  8 MB  x as bf16
  u16* WaT = (u16*)(ws + (8u  << 20)); //  6 MB  W_attn^T bf16
  u16* WpT = (u16*)(ws + (14u << 20)); //  2 MB  W_proj^T bf16
  u16* Qb  = (u16*)(ws + (16u << 20)); //  8 MB  [B*H][T][D]  (pre-scaled)
  u16* Kb  = (u16*)(ws + (24u << 20)); //  8 MB
  u16* Vtb = (u16*)(ws + (32u << 20)); //  8 MB  V^T [B*H][D][T] (written by qkv)
  u16* Yb  = (u16*)(ws + (40u << 20)); //  8 MB  attn out bf16

  k_prep<<<dim3(6144), dim3(256), 0, stream>>>(x, xb, W_attn, WaT, W_proj, WpT);
  k_gemm_qkv<<<dim3(24, 32), dim3(256), 0, stream>>>(xb, WaT, b_attn, Qb, Kb, Vtb);
  k_flash<<<dim3(512), dim3(1024), 0, stream>>>(Qb, Kb, Vtb, Yb);
  k_gemm_proj<<<dim3(8, 64), dim3(256), 0, stream>>>(Yb, WpT, b_proj, out);
}

// Round 21
// 102.760 us; speedup vs baseline: 2.6026x; 2.6026x over previous
//
#include <hip/hip_runtime.h>
#include <stdint.h>

typedef float f32x4 __attribute__((ext_vector_type(4)));
typedef float f32x16 __attribute__((ext_vector_type(16)));
typedef __bf16 bf16x8 __attribute__((ext_vector_type(8)));
typedef unsigned short ushort8 __attribute__((ext_vector_type(8)));
typedef unsigned int uint4v __attribute__((ext_vector_type(4)));
typedef unsigned short u16;

#define DEVINL static __device__ __forceinline__

#define EXP2(x) exp2f(x)

// counted vmcnt wait (N = loads allowed to stay in flight), order-pinned
#define VMCNT(N)                                          \
  {                                                       \
    asm volatile("s_waitcnt vmcnt(" #N ")" ::: "memory"); \
    __builtin_amdgcn_sched_barrier(0);                    \
  }

// raw workgroup barrier WITHOUT the __syncthreads vmcnt(0) drain
DEVINL void barrier_raw() {
  __builtin_amdgcn_sched_barrier(0);
  __builtin_amdgcn_s_barrier();
  __builtin_amdgcn_sched_barrier(0);
}

// fp32 -> bf16 via native convert (RNE)
DEVINL u16 f2bf(float f) {
  __bf16 h = (__bf16)f;
  return __builtin_bit_cast(u16, h);
}

// packed fp32x2 -> bf16x2 (no builtin on gfx950; inline asm per T12)
DEVINL unsigned cvtpk(float lo, float hi) {
  unsigned r;
  asm("v_cvt_pk_bf16_f32 %0, %1, %2" : "=v"(r) : "v"(lo), "v"(hi));
  return r;
}

// exchange lanes [32..63] of a with lanes [0..31] of b (VALU cross-lane)
DEVINL void plswap(unsigned& a, unsigned& b) {
  asm("v_permlane32_swap_b32 %0, %1" : "+v"(a), "+v"(b));
}

// async global->LDS, 16B per lane. LDS dest must be wave-uniform base + lane*16.
DEVINL void gload16(const void* g, void* l) {
  __builtin_amdgcn_global_load_lds((__attribute__((address_space(1))) void*)g,
                                   (__attribute__((address_space(3))) void*)l, 16, 0, 0);
}

DEVINL f32x4 mfma16(bf16x8 a, bf16x8 b, f32x4 c) {
  return __builtin_amdgcn_mfma_f32_16x16x32_bf16(a, b, c, 0, 0, 0);
}
DEVINL f32x16 mfma32(bf16x8 a, bf16x8 b, f32x16 c) {
  return __builtin_amdgcn_mfma_f32_32x32x16_bf16(a, b, c, 0, 0, 0);
}

// ---------------- fused prep: cast x -> bf16 + transpose-cast both weights --------
__global__ __launch_bounds__(256) void k_prep(const float* __restrict__ x,
                                              u16* __restrict__ xb,
                                              const float* __restrict__ Wa,
                                              u16* __restrict__ WaT,
                                              const float* __restrict__ Wp,
                                              u16* __restrict__ WpT) {
  __shared__ float tile[32][33];
  const int bid = blockIdx.x;
  if (bid < 2048) {
    const int i = bid * 256 + threadIdx.x;
    const float4* p = (const float4*)x + (size_t)i * 2;
    float4 a = p[0], b = p[1];
    ushort8 o;
    o[0] = f2bf(a.x); o[1] = f2bf(a.y); o[2] = f2bf(a.z); o[3] = f2bf(a.w);
    o[4] = f2bf(b.x); o[5] = f2bf(b.y); o[6] = f2bf(b.z); o[7] = f2bf(b.w);
    *((ushort8*)xb + i) = o;
    return;
  }
  const float* in;
  u16* out;
  int C, cx, ry;
  if (bid < 5120) {
    const int bx = bid - 2048;
    in = Wa; out = WaT; C = 3072; cx = bx % 96; ry = bx / 96;
  } else {
    const int bx = bid - 5120;
    in = Wp; out = WpT; C = 1024; cx = bx & 31; ry = bx >> 5;
  }
  const int tx = threadIdx.x & 31, ty = threadIdx.x >> 5;
  const int c0 = cx * 32, r0 = ry * 32;
#pragma unroll
  for (int k = 0; k < 4; ++k)
    tile[ty + k * 8][tx] = in[(size_t)(r0 + ty + k * 8) * C + (c0 + tx)];
  __syncthreads();
#pragma unroll
  for (int k = 0; k < 4; ++k)
    out[(size_t)(c0 + ty + k * 8) * 1024 + (r0 + tx)] = f2bf(tile[tx][ty + k * 8]);
}

// ---------------- staging: ROWS x 64 bf16 tile via global_load_lds, XOR swizzle ----
template <int ROWS>
DEVINL void stageRx64(const u16* __restrict__ g, int ld, u16* lds, int t) {
#pragma unroll
  for (int i = 0; i < ROWS / 32; ++i) {
    int ci = i * 256 + t;
    int row = ci >> 3, gr = ci & 7;
    int gs = gr ^ (row & 7);
    gload16(g + (size_t)row * ld + gs * 8, lds + ci * 8);
  }
}

// ---------------- staging: ROWS x 32 bf16 tile (BK=32), conflict-free swizzle -----
template <int ROWS>
DEVINL void stageRx32(const u16* __restrict__ g, int ld, u16* lds, int t) {
#pragma unroll
  for (int i = 0; i < ROWS / 64; ++i) {
    int ci = i * 256 + t;
    int row = ci >> 2, gr = ci & 3;
    int gs = gr ^ ((row >> 1) & 3);
    gload16(g + (size_t)row * ld + gs * 8, lds + ci * 8);
  }
}

// ---------------- GEMM core: 128x128 tile, BK=32, 32KB LDS -> 3+/CU ---------------
DEVINL void gemm_core_128b32(const u16* __restrict__ A, const u16* __restrict__ B,
                             int Kdim, u16* As, u16* Bs, int t, f32x4 acc[4][4]) {
  const int l = t & 63, lr = l & 15, lg = l >> 4;
  const int wr = t >> 7, wc = (t >> 6) & 1;
  const int nk = Kdim >> 5;  // BK=32
  stageRx32<128>(A, Kdim, As, t);
  stageRx32<128>(B, Kdim, Bs, t);
  for (int kt = 0; kt < nk; ++kt) {
    if (kt + 1 < nk) {
      stageRx32<128>(A + (kt + 1) * 32, Kdim, As + ((kt + 1) & 1) * 4096, t);
      stageRx32<128>(B + (kt + 1) * 32, Kdim, Bs + ((kt + 1) & 1) * 4096, t);
      VMCNT(4);
    } else {
      VMCNT(0);
    }
    barrier_raw();
    const u16* Asc = As + (kt & 1) * 4096;
    const u16* Bsc = Bs + (kt & 1) * 4096;
    bf16x8 af[4], bf[4];
#pragma unroll
    for (int mi = 0; mi < 4; ++mi) {
      int r = wr * 64 + mi * 16 + lr;
      int g = lg ^ ((r >> 1) & 3);
      af[mi] = *(const bf16x8*)(Asc + r * 32 + g * 8);
    }
#pragma unroll
    for (int ni = 0; ni < 4; ++ni) {
      int r = wc * 64 + ni * 16 + lr;
      int g = lg ^ ((r >> 1) & 3);
      bf[ni] = *(const bf16x8*)(Bsc + r * 32 + g * 8);
    }
#pragma unroll
    for (int mi = 0; mi < 4; ++mi)
#pragma unroll
      for (int ni = 0; ni < 4; ++ni)
        acc[mi][ni] = mfma16(af[mi], bf[ni], acc[mi][ni]);
    barrier_raw();
  }
}

// ---------------- GEMM core: 64x128 tile (proj, proven) ---------------------------
DEVINL void gemm_core_64(const u16* __restrict__ A, const u16* __restrict__ B,
                         int Kdim, u16* As, u16* Bs, int t, f32x4 acc[2][4]) {
  const int l = t & 63, lr = l & 15, lg = l >> 4;
  const int wr = t >> 7, wc = (t >> 6) & 1;
  const int nk = Kdim >> 6;
  stageRx64<64>(A, Kdim, As, t);
  stageRx64<128>(B, Kdim, Bs, t);
  for (int kt = 0; kt < nk; ++kt) {
    if (kt + 1 < nk) {
      stageRx64<64>(A + (kt + 1) * 64, Kdim, As + ((kt + 1) & 1) * 4096, t);
      stageRx64<128>(B + (kt + 1) * 64, Kdim, Bs + ((kt + 1) & 1) * 8192, t);
      VMCNT(6);
    } else {
      VMCNT(0);
    }
    barrier_raw();
    const u16* Asc = As + (kt & 1) * 4096;
    const u16* Bsc = Bs + (kt & 1) * 8192;
#pragma unroll
    for (int ks = 0; ks < 2; ++ks) {
      bf16x8 af[2], bf[4];
#pragma unroll
      for (int mi = 0; mi < 2; ++mi) {
        int r = wr * 32 + mi * 16 + lr;
        int g = (ks * 4 + lg) ^ (r & 7);
        af[mi] = *(const bf16x8*)(Asc + r * 64 + g * 8);
      }
#pragma unroll
      for (int ni = 0; ni < 4; ++ni) {
        int r = wc * 64 + ni * 16 + lr;
        int g = (ks * 4 + lg) ^ (r & 7);
        bf[ni] = *(const bf16x8*)(Bsc + r * 64 + g * 8);
      }
#pragma unroll
      for (int mi = 0; mi < 2; ++mi)
#pragma unroll
        for (int ni = 0; ni < 4; ++ni)
          acc[mi][ni] = mfma16(af[mi], bf[ni], acc[mi][ni]);
    }
    barrier_raw();
  }
}

// ---------------- GEMM 1: qkv = xb @ W_attn + b -> Q/K [BH][T][D], V^T [BH][D][T] --
__global__ __launch_bounds__(256) void k_gemm_qkv(const u16* __restrict__ xb,
                                                  const u16* __restrict__ WaT,
                                                  const float* __restrict__ b_attn,
                                                  u16* __restrict__ Qo,
                                                  u16* __restrict__ Ko,
                                                  u16* __restrict__ Vto) {
  __shared__ u16 As[2 * 128 * 32], Bs[2 * 128 * 32];  // 32 KB
  const int t = threadIdx.x;
  const int m0 = blockIdx.y * 128, n0 = blockIdx.x * 128;
  f32x4 acc[4][4] = {};
  gemm_core_128b32(xb + (size_t)m0 * 1024, WaT + (size_t)n0 * 1024, 1024, As, Bs, t,
                   acc);
  const int l = t & 63, lr = l & 15, lg = l >> 4;
  const int wr = t >> 7, wc = (t >> 6) & 1;
#pragma unroll
  for (int ni = 0; ni < 4; ++ni) {
    const int gcol = n0 + wc * 64 + ni * 16 + lr;
    const int part = gcol >> 10;
    const int h = (gcol & 1023) >> 6, d = gcol & 63;
    const float bias = b_attn[gcol];
    if (part == 2) {
      // V: write transposed directly -> Vt[bh][d][t]
#pragma unroll
      for (int mi = 0; mi < 4; ++mi) {
        const int tt0 = m0 + wr * 64 + mi * 16 + lg * 4;
        const int bb = tt0 >> 11, tt = tt0 & 2047;
        ushort4 pk;
        pk.x = f2bf(acc[mi][ni][0] + bias);
        pk.y = f2bf(acc[mi][ni][1] + bias);
        pk.z = f2bf(acc[mi][ni][2] + bias);
        pk.w = f2bf(acc[mi][ni][3] + bias);
        *(ushort4*)(Vto + (size_t)(bb * 16 + h) * 131072 + (size_t)d * 2048 + tt) = pk;
      }
    } else {
      const float osc = (part == 0) ? 0.18033688f : 1.0f;  // 0.125 * log2(e)
      u16* dst = (part == 0) ? Qo : Ko;
#pragma unroll
      for (int mi = 0; mi < 4; ++mi)
#pragma unroll
        for (int r = 0; r < 4; ++r) {
          const int grow = m0 + wr * 64 + mi * 16 + lg * 4 + r;
          const int bb = grow >> 11, tt = grow & 2047;
          dst[(size_t)((bb * 16 + h) * 2048 + tt) * 64 + d] =
              f2bf((acc[mi][ni][r] + bias) * osc);
        }
    }
  }
}

// ---------------- GEMM 2: out = Y @ W_proj + b (fp32 out), 64x128 tiles ----------
__global__ __launch_bounds__(256) void k_gemm_proj(const u16* __restrict__ Yb,
                                                   const u16* __restrict__ WpT,
                                                   const float* __restrict__ b_proj,
                                                   float* __restrict__ out) {
  __shared__ u16 As[2 * 64 * 64], Bs[2 * 128 * 64];  // 48 KB
  const int t = threadIdx.x;
  const int m0 = blockIdx.y * 64, n0 = blockIdx.x * 128;
  f32x4 acc[2][4] = {};
  gemm_core_64(Yb + (size_t)m0 * 1024, WpT + (size_t)n0 * 1024, 1024, As, Bs, t, acc);
  const int l = t & 63, lr = l & 15, lg = l >> 4;
  const int wr = t >> 7, wc = (t >> 6) & 1;
#pragma unroll
  for (int ni = 0; ni < 4; ++ni) {
    const int gcol = n0 + wc * 64 + ni * 16 + lr;
    const float bias = b_proj[gcol];
#pragma unroll
    for (int mi = 0; mi < 2; ++mi)
#pragma unroll
      for (int r = 0; r < 4; ++r) {
        const int grow = m0 + wr * 32 + mi * 16 + lg * 4 + r;
        out[(size_t)grow * 1024 + gcol] = acc[mi][ni][r] + bias;
      }
  }
}

// ---------------- flash attention (causal), r18 codegen, 512-block grid ----------
// __launch_bounds__(1024,4) keeps r18's codegen (VGPR=60, no spill). Since
// 60 <= 64 and LDS 71.7KB*2 <= 160KB, HARDWARE occupancy = 2 blocks/CU with
// the 512-block grid (r18 only had 256 blocks -> 1/CU). Complementary pairing
// (bid, bid+256) -> (qt, 15-qt); XCD map bid&7 keeps K/V L2-resident.
__global__ __launch_bounds__(1024, 4) void k_flash(const u16* __restrict__ Q,
                                                   const u16* __restrict__ K,
                                                   const u16* __restrict__ Vt,
                                                   u16* __restrict__ Y) {
  __shared__ u16 SM[2 * 9216 + 2 * 8704];  // 71,680 B
  u16* KsB = SM;                           // [2][128*72]
  u16* VsB = SM + 2 * 9216;                // [2][64*136]
  float* Ms = (float*)SM;                  // merge alias (post-loop)

  const int t = threadIdx.x, l = t & 63, w = t >> 6;
  const int ql = l & 31, hi = l >> 5;
  const int wq = w & 3, wk = w >> 2;
  const int bid = blockIdx.x;
  const int bh = (bid & 7) + 8 * ((bid >> 3) & 3);  // 4 bh per XCD
  const int jj = (bid >> 5) & 7;
  const int qt = (bid >> 8) ? (15 - jj) : jj;       // complementary pairs
  const size_t base = (size_t)bh * 131072;
  const int b = bh >> 4, hh = bh & 15;
  const int srow = t >> 3, scol = t & 7;  // K tile: 128 rows x 8 granules
  const int sd = t >> 4, sck = t & 15;    // V tile: 64 d-rows x 16 key-granules

  const int nsteps = qt + 1;  // 128-key kv tiles
  const int qbase = qt * 128 + wq * 32;
  const int qrow = qbase + ql;

  bf16x8 qb[4];
#pragma unroll
  for (int m = 0; m < 4; ++m)
    qb[m] = *(const bf16x8*)(Q + base + (size_t)qrow * 64 + hi * 8 + 16 * m);

  {
    ushort8 kv = *(const ushort8*)(K + base + (size_t)srow * 64 + scol * 8);
    ushort8 vv = *(const ushort8*)(Vt + base + (size_t)sd * 2048 + sck * 8);
    *(ushort8*)(KsB + srow * 72 + scol * 8) = kv;
    *(ushort8*)(VsB + sd * 136 + sck * 8) = vv;
  }
  __syncthreads();

  f32x16 accO0 = {}, accO1 = {};  // O^T: q=ql, d=(r&3)+8*(r>>2)+4*hi (+32)
  float rs_lane = 0.f;
  const int krow = wk * 32 + ql;

  for (int n = 0; n < nsteps; ++n) {
    const u16* Kc = KsB + (n & 1) * 9216;
    const u16* Vc = VsB + (n & 1) * 8704;
    const bool more = (n + 1 < nsteps);
    ushort8 kv, vv;
    if (more) {  // issue next-tile loads early; land under compute
      kv = *(const ushort8*)(K + base + (size_t)((n + 1) * 128 + srow) * 64 + scol * 8);
      vv = *(const ushort8*)(Vt + base + (size_t)sd * 2048 + (n + 1) * 128 + sck * 8);
    }
    const int kbase = n * 128 + wk * 32;
    if (kbase <= qbase + 31) {  // else fully masked for this wave
      f32x16 st = {};
      __builtin_amdgcn_s_setprio(1);
#pragma unroll
      for (int m = 0; m < 4; ++m) {
        bf16x8 ka = *(const bf16x8*)(Kc + krow * 72 + (hi + 2 * m) * 8);
        st = mfma32(ka, qb[m], st);
      }
      __builtin_amdgcn_s_setprio(0);
      if (kbase + 31 > qbase) {  // diagonal: causal mask
#pragma unroll
        for (int r = 0; r < 16; ++r) {
          const int keyl = (r & 3) + 8 * (r >> 2) + 4 * hi;
          if (kbase + keyl > qrow) st[r] = -1e30f;
        }
      }
      float pp[16];
#pragma unroll
      for (int r = 0; r < 16; ++r) {
        pp[r] = EXP2(st[r]);
        rs_lane += pp[r];
      }
      unsigned uu[8];
#pragma unroll
      for (int i = 0; i < 8; ++i) uu[i] = cvtpk(pp[2 * i], pp[2 * i + 1]);
      plswap(uu[0], uu[2]);
      plswap(uu[1], uu[3]);
      plswap(uu[4], uu[6]);
      plswap(uu[5], uu[7]);
      uint4v w0 = {uu[0], uu[1], uu[2], uu[3]};
      uint4v w1 = {uu[4], uu[5], uu[6], uu[7]};
      bf16x8 pf0 = __builtin_bit_cast(bf16x8, w0);
      bf16x8 pf1 = __builtin_bit_cast(bf16x8, w1);
      __builtin_amdgcn_s_setprio(1);
      {
        bf16x8 va0 = *(const bf16x8*)(Vc + ql * 136 + (4 * wk + hi) * 8);
        bf16x8 va1 = *(const bf16x8*)(Vc + ql * 136 + (4 * wk + 2 + hi) * 8);
        accO0 = mfma32(va0, pf0, accO0);
        accO0 = mfma32(va1, pf1, accO0);
        bf16x8 vb0 = *(const bf16x8*)(Vc + (32 + ql) * 136 + (4 * wk + hi) * 8);
        bf16x8 vb1 = *(const bf16x8*)(Vc + (32 + ql) * 136 + (4 * wk + 2 + hi) * 8);
        accO1 = mfma32(vb0, pf0, accO1);
        accO1 = mfma32(vb1, pf1, accO1);
      }
      __builtin_amdgcn_s_setprio(0);
    }
    if (more) {  // write next tile (compiler inserts vmcnt for kv/vv)
      u16* Kn = KsB + ((n + 1) & 1) * 9216;
      u16* Vn = VsB + ((n + 1) & 1) * 8704;
      *(ushort8*)(Kn + srow * 72 + scol * 8) = kv;
      *(ushort8*)(Vn + sd * 136 + sck * 8) = vv;
    }
    __syncthreads();  // writes visible; everyone done reading buf[n&1]
  }

  rs_lane += __shfl_xor(rs_lane, 32);

  // hierarchical 4-way wk merge (Ms aliases dead K/V buffers)
  {
    float* Mp = Ms + (size_t)(((wq * 2 + (wk >> 1)) * 64 + l)) * 33;
    if (wk & 1) {
#pragma unroll
      for (int i = 0; i < 16; ++i) Mp[i] = accO0[i];
#pragma unroll
      for (int i = 0; i < 16; ++i) Mp[16 + i] = accO1[i];
      Mp[32] = rs_lane;
    }
    __syncthreads();
    if (!(wk & 1)) {
#pragma unroll
      for (int i = 0; i < 16; ++i) accO0[i] += Mp[i];
#pragma unroll
      for (int i = 0; i < 16; ++i) accO1[i] += Mp[16 + i];
      rs_lane += Mp[32];
    }
    __syncthreads();
  }
  {
    float* Mp = Ms + (size_t)((wq * 64 + l)) * 33;
    if (wk == 2) {
#pragma unroll
      for (int i = 0; i < 16; ++i) Mp[i] = accO0[i];
#pragma unroll
      for (int i = 0; i < 16; ++i) Mp[16 + i] = accO1[i];
      Mp[32] = rs_lane;
    }
    __syncthreads();
    if (wk == 0) {
      const float inv = 1.0f / (rs_lane + Mp[32]);
      u16* yb = Y + ((size_t)(b * 2048 + qrow)) * 1024 + hh * 64;
#pragma unroll
      for (int rq = 0; rq < 4; ++rq) {
        const int d0 = 8 * rq + 4 * hi;
        ushort4 o4;
        o4.x = f2bf((accO0[rq * 4 + 0] + Mp[rq * 4 + 0]) * inv);
        o4.y = f2bf((accO0[rq * 4 + 1] + Mp[rq * 4 + 1]) * inv);
        o4.z = f2bf((accO0[rq * 4 + 2] + Mp[rq * 4 + 2]) * inv);
        o4.w = f2bf((accO0[rq * 4 + 3] + Mp[rq * 4 + 3]) * inv);
        *(ushort4*)(yb + d0) = o4;
      }
#pragma unroll
      for (int rq = 0; rq < 4; ++rq) {
        const int d0 = 32 + 8 * rq + 4 * hi;
        ushort4 o4;
        o4.x = f2bf((accO1[rq * 4 + 0] + Mp[16 + rq * 4 + 0]) * inv);
        o4.y = f2bf((accO1[rq * 4 + 1] + Mp[16 + rq * 4 + 1]) * inv);
        o4.z = f2bf((accO1[rq * 4 + 2] + Mp[16 + rq * 4 + 2]) * inv);
        o4.w = f2bf((accO1[rq * 4 + 3] + Mp[16 + rq * 4 + 3]) * inv);
        *(ushort4*)(yb + d0) = o4;
      }
    }
  }
}

// ---------------- launch ----------------
extern "C" void kernel_launch(void* const* d_in, const int* in_sizes, int n_in,
                              void* d_out, int out_size, void* d_ws, size_t ws_size,
                              hipStream_t stream) {
  const float* x      = (const float*)d_in[0];
  const float* W_attn = (const float*)d_in[1];
  const float* b_attn = (const float*)d_in[2];
  const float* W_proj = (const float*)d_in[3];
  const float* b_proj = (const float*)d_in[4];
  float* out = (float*)d_out;

  char* ws = (char*)d_ws;              // 48 MB total
  u16* xb  = (u16*)(ws);               //  8 MB  x as bf16
  u16* WaT = (u16*)(ws + (8u  << 20)); //  6 MB  W_attn^T bf16
  u16* WpT = (u16*)(ws + (14u << 20)); //  2 MB  W_proj^T bf16
  u16* Qb  = (u16*)(ws + (16u << 20)); //  8 MB  [B*H][T][D]  (pre-scaled)
  u16* Kb  = (u16*)(ws + (24u << 20)); //  8 MB
  u16* Vtb = (u16*)(ws + (32u << 20)); //  8 MB  V^T [B*H][D][T] (written by qkv)
  u16* Yb  = (u16*)(ws + (40u << 20)); //  8 MB  attn out bf16

  k_prep<<<dim3(6144), dim3(256), 0, stream>>>(x, xb, W_attn, WaT, W_proj, WpT);
  k_gemm_qkv<<<dim3(24, 32), dim3(256), 0, stream>>>(xb, WaT, b_attn, Qb, Kb, Vtb);
  k_flash<<<dim3(512), dim3(1024), 0, stream>>>(Qb, Kb, Vtb, Yb);
  k_gemm_proj<<<dim3(8, 64), dim3(256), 0, stream>>>(Yb, WpT, b_proj, out);
}

// Round 22
// 99.704 us; speedup vs baseline: 2.6824x; 1.0306x over previous
//
#include <hip/hip_runtime.h>
#include <stdint.h>

typedef float f32x4 __attribute__((ext_vector_type(4)));
typedef float f32x16 __attribute__((ext_vector_type(16)));
typedef __bf16 bf16x8 __attribute__((ext_vector_type(8)));
typedef unsigned short ushort8 __attribute__((ext_vector_type(8)));
typedef unsigned int uint4v __attribute__((ext_vector_type(4)));
typedef unsigned short u16;

#define DEVINL static __device__ __forceinline__

#define EXP2(x) exp2f(x)

// counted vmcnt wait (N = loads allowed to stay in flight), order-pinned
#define VMCNT(N)                                          \
  {                                                       \
    asm volatile("s_waitcnt vmcnt(" #N ")" ::: "memory"); \
    __builtin_amdgcn_sched_barrier(0);                    \
  }

// raw workgroup barrier WITHOUT the __syncthreads vmcnt(0) drain
DEVINL void barrier_raw() {
  __builtin_amdgcn_sched_barrier(0);
  __builtin_amdgcn_s_barrier();
  __builtin_amdgcn_sched_barrier(0);
}

// fp32 -> bf16 via native convert (RNE)
DEVINL u16 f2bf(float f) {
  __bf16 h = (__bf16)f;
  return __builtin_bit_cast(u16, h);
}

// packed fp32x2 -> bf16x2 (no builtin on gfx950; inline asm per T12)
DEVINL unsigned cvtpk(float lo, float hi) {
  unsigned r;
  asm("v_cvt_pk_bf16_f32 %0, %1, %2" : "=v"(r) : "v"(lo), "v"(hi));
  return r;
}

// exchange lanes [32..63] of a with lanes [0..31] of b (VALU cross-lane)
DEVINL void plswap(unsigned& a, unsigned& b) {
  asm("v_permlane32_swap_b32 %0, %1" : "+v"(a), "+v"(b));
}

// async global->LDS, 16B per lane. LDS dest must be wave-uniform base + lane*16.
DEVINL void gload16(const void* g, void* l) {
  __builtin_amdgcn_global_load_lds((__attribute__((address_space(1))) void*)g,
                                   (__attribute__((address_space(3))) void*)l, 16, 0, 0);
}

DEVINL f32x4 mfma16(bf16x8 a, bf16x8 b, f32x4 c) {
  return __builtin_amdgcn_mfma_f32_16x16x32_bf16(a, b, c, 0, 0, 0);
}
DEVINL f32x16 mfma32(bf16x8 a, bf16x8 b, f32x16 c) {
  return __builtin_amdgcn_mfma_f32_32x32x16_bf16(a, b, c, 0, 0, 0);
}

// ---------------- fused prep: cast x -> bf16 + transpose-cast both weights --------
__global__ __launch_bounds__(256) void k_prep(const float* __restrict__ x,
                                              u16* __restrict__ xb,
                                              const float* __restrict__ Wa,
                                              u16* __restrict__ WaT,
                                              const float* __restrict__ Wp,
                                              u16* __restrict__ WpT) {
  __shared__ float tile[32][33];
  const int bid = blockIdx.x;
  if (bid < 2048) {
    const int i = bid * 256 + threadIdx.x;
    const float4* p = (const float4*)x + (size_t)i * 2;
    float4 a = p[0], b = p[1];
    ushort8 o;
    o[0] = f2bf(a.x); o[1] = f2bf(a.y); o[2] = f2bf(a.z); o[3] = f2bf(a.w);
    o[4] = f2bf(b.x); o[5] = f2bf(b.y); o[6] = f2bf(b.z); o[7] = f2bf(b.w);
    *((ushort8*)xb + i) = o;
    return;
  }
  const float* in;
  u16* out;
  int C, cx, ry;
  if (bid < 5120) {
    const int bx = bid - 2048;
    in = Wa; out = WaT; C = 3072; cx = bx % 96; ry = bx / 96;
  } else {
    const int bx = bid - 5120;
    in = Wp; out = WpT; C = 1024; cx = bx & 31; ry = bx >> 5;
  }
  const int tx = threadIdx.x & 31, ty = threadIdx.x >> 5;
  const int c0 = cx * 32, r0 = ry * 32;
#pragma unroll
  for (int k = 0; k < 4; ++k)
    tile[ty + k * 8][tx] = in[(size_t)(r0 + ty + k * 8) * C + (c0 + tx)];
  __syncthreads();
#pragma unroll
  for (int k = 0; k < 4; ++k)
    out[(size_t)(c0 + ty + k * 8) * 1024 + (r0 + tx)] = f2bf(tile[tx][ty + k * 8]);
}

// ---------------- staging: ROWS x 64 bf16 tile via global_load_lds, XOR swizzle ----
template <int ROWS>
DEVINL void stageRx64(const u16* __restrict__ g, int ld, u16* lds, int t) {
#pragma unroll
  for (int i = 0; i < ROWS / 32; ++i) {
    int ci = i * 256 + t;
    int row = ci >> 3, gr = ci & 7;
    int gs = gr ^ (row & 7);
    gload16(g + (size_t)row * ld + gs * 8, lds + ci * 8);
  }
}

// ---------------- staging: ROWS x 32 bf16 tile (BK=32), conflict-free swizzle -----
template <int ROWS>
DEVINL void stageRx32(const u16* __restrict__ g, int ld, u16* lds, int t) {
#pragma unroll
  for (int i = 0; i < ROWS / 64; ++i) {
    int ci = i * 256 + t;
    int row = ci >> 2, gr = ci & 3;
    int gs = gr ^ ((row >> 1) & 3);
    gload16(g + (size_t)row * ld + gs * 8, lds + ci * 8);
  }
}

// ---------------- GEMM core: 128x128 tile, BK=32, 32KB LDS -> 3+/CU ---------------
DEVINL void gemm_core_128b32(const u16* __restrict__ A, const u16* __restrict__ B,
                             int Kdim, u16* As, u16* Bs, int t, f32x4 acc[4][4]) {
  const int l = t & 63, lr = l & 15, lg = l >> 4;
  const int wr = t >> 7, wc = (t >> 6) & 1;
  const int nk = Kdim >> 5;  // BK=32
  stageRx32<128>(A, Kdim, As, t);
  stageRx32<128>(B, Kdim, Bs, t);
  for (int kt = 0; kt < nk; ++kt) {
    if (kt + 1 < nk) {
      stageRx32<128>(A + (kt + 1) * 32, Kdim, As + ((kt + 1) & 1) * 4096, t);
      stageRx32<128>(B + (kt + 1) * 32, Kdim, Bs + ((kt + 1) & 1) * 4096, t);
      VMCNT(4);
    } else {
      VMCNT(0);
    }
    barrier_raw();
    const u16* Asc = As + (kt & 1) * 4096;
    const u16* Bsc = Bs + (kt & 1) * 4096;
    bf16x8 af[4], bf[4];
#pragma unroll
    for (int mi = 0; mi < 4; ++mi) {
      int r = wr * 64 + mi * 16 + lr;
      int g = lg ^ ((r >> 1) & 3);
      af[mi] = *(const bf16x8*)(Asc + r * 32 + g * 8);
    }
#pragma unroll
    for (int ni = 0; ni < 4; ++ni) {
      int r = wc * 64 + ni * 16 + lr;
      int g = lg ^ ((r >> 1) & 3);
      bf[ni] = *(const bf16x8*)(Bsc + r * 32 + g * 8);
    }
#pragma unroll
    for (int mi = 0; mi < 4; ++mi)
#pragma unroll
      for (int ni = 0; ni < 4; ++ni)
        acc[mi][ni] = mfma16(af[mi], bf[ni], acc[mi][ni]);
    barrier_raw();
  }
}

// ---------------- GEMM core: 64x128 tile (proj, proven) ---------------------------
DEVINL void gemm_core_64(const u16* __restrict__ A, const u16* __restrict__ B,
                         int Kdim, u16* As, u16* Bs, int t, f32x4 acc[2][4]) {
  const int l = t & 63, lr = l & 15, lg = l >> 4;
  const int wr = t >> 7, wc = (t >> 6) & 1;
  const int nk = Kdim >> 6;
  stageRx64<64>(A, Kdim, As, t);
  stageRx64<128>(B, Kdim, Bs, t);
  for (int kt = 0; kt < nk; ++kt) {
    if (kt + 1 < nk) {
      stageRx64<64>(A + (kt + 1) * 64, Kdim, As + ((kt + 1) & 1) * 4096, t);
      stageRx64<128>(B + (kt + 1) * 64, Kdim, Bs + ((kt + 1) & 1) * 8192, t);
      VMCNT(6);
    } else {
      VMCNT(0);
    }
    barrier_raw();
    const u16* Asc = As + (kt & 1) * 4096;
    const u16* Bsc = Bs + (kt & 1) * 8192;
#pragma unroll
    for (int ks = 0; ks < 2; ++ks) {
      bf16x8 af[2], bf[4];
#pragma unroll
      for (int mi = 0; mi < 2; ++mi) {
        int r = wr * 32 + mi * 16 + lr;
        int g = (ks * 4 + lg) ^ (r & 7);
        af[mi] = *(const bf16x8*)(Asc + r * 64 + g * 8);
      }
#pragma unroll
      for (int ni = 0; ni < 4; ++ni) {
        int r = wc * 64 + ni * 16 + lr;
        int g = (ks * 4 + lg) ^ (r & 7);
        bf[ni] = *(const bf16x8*)(Bsc + r * 64 + g * 8);
      }
#pragma unroll
      for (int mi = 0; mi < 2; ++mi)
#pragma unroll
        for (int ni = 0; ni < 4; ++ni)
          acc[mi][ni] = mfma16(af[mi], bf[ni], acc[mi][ni]);
    }
    barrier_raw();
  }
}

// ---------------- GEMM 1: qkv = xb @ W_attn + b -> Q/K [BH][T][D], V^T [BH][D][T] --
// Flat 768-block grid with XCD-aware remap (T1): each XCD owns an 8x12 (by,bx)
// rectangle -> A working set 2MB + B 3MB per XCD L2 (was: A thrashing 8MB).
__global__ __launch_bounds__(256) void k_gemm_qkv(const u16* __restrict__ xb,
                                                  const u16* __restrict__ WaT,
                                                  const float* __restrict__ b_attn,
                                                  u16* __restrict__ Qo,
                                                  u16* __restrict__ Ko,
                                                  u16* __restrict__ Vto) {
  __shared__ u16 As[2 * 128 * 32], Bs[2 * 128 * 32];  // 32 KB
  const int t = threadIdx.x;
  const int bid = blockIdx.x;
  const int xcd = bid & 7;     // measured i%8 XCD round-robin
  const int j = bid >> 3;      // 0..95 within XCD
  const int by = ((xcd >> 1) << 3) + (j & 7);   // 4 by-groups of 8
  const int bx = (xcd & 1) * 12 + (j >> 3);     // 2 bx-groups of 12
  const int m0 = by * 128, n0 = bx * 128;
  f32x4 acc[4][4] = {};
  gemm_core_128b32(xb + (size_t)m0 * 1024, WaT + (size_t)n0 * 1024, 1024, As, Bs, t,
                   acc);
  const int l = t & 63, lr = l & 15, lg = l >> 4;
  const int wr = t >> 7, wc = (t >> 6) & 1;
#pragma unroll
  for (int ni = 0; ni < 4; ++ni) {
    const int gcol = n0 + wc * 64 + ni * 16 + lr;
    const int part = gcol >> 10;
    const int h = (gcol & 1023) >> 6, d = gcol & 63;
    const float bias = b_attn[gcol];
    if (part == 2) {
      // V: write transposed directly -> Vt[bh][d][t]
#pragma unroll
      for (int mi = 0; mi < 4; ++mi) {
        const int tt0 = m0 + wr * 64 + mi * 16 + lg * 4;
        const int bb = tt0 >> 11, tt = tt0 & 2047;
        ushort4 pk;
        pk.x = f2bf(acc[mi][ni][0] + bias);
        pk.y = f2bf(acc[mi][ni][1] + bias);
        pk.z = f2bf(acc[mi][ni][2] + bias);
        pk.w = f2bf(acc[mi][ni][3] + bias);
        *(ushort4*)(Vto + (size_t)(bb * 16 + h) * 131072 + (size_t)d * 2048 + tt) = pk;
      }
    } else {
      const float osc = (part == 0) ? 0.18033688f : 1.0f;  // 0.125 * log2(e)
      u16* dst = (part == 0) ? Qo : Ko;
#pragma unroll
      for (int mi = 0; mi < 4; ++mi)
#pragma unroll
        for (int r = 0; r < 4; ++r) {
          const int grow = m0 + wr * 64 + mi * 16 + lg * 4 + r;
          const int bb = grow >> 11, tt = grow & 2047;
          dst[(size_t)((bb * 16 + h) * 2048 + tt) * 64 + d] =
              f2bf((acc[mi][ni][r] + bias) * osc);
        }
    }
  }
}

// ---------------- GEMM 2: out = Y @ W_proj + b (fp32 out), 64x128 tiles ----------
__global__ __launch_bounds__(256) void k_gemm_proj(const u16* __restrict__ Yb,
                                                   const u16* __restrict__ WpT,
                                                   const float* __restrict__ b_proj,
                                                   float* __restrict__ out) {
  __shared__ u16 As[2 * 64 * 64], Bs[2 * 128 * 64];  // 48 KB
  const int t = threadIdx.x;
  const int m0 = blockIdx.y * 64, n0 = blockIdx.x * 128;
  f32x4 acc[2][4] = {};
  gemm_core_64(Yb + (size_t)m0 * 1024, WpT + (size_t)n0 * 1024, 1024, As, Bs, t, acc);
  const int l = t & 63, lr = l & 15, lg = l >> 4;
  const int wr = t >> 7, wc = (t >> 6) & 1;
#pragma unroll
  for (int ni = 0; ni < 4; ++ni) {
    const int gcol = n0 + wc * 64 + ni * 16 + lr;
    const float bias = b_proj[gcol];
#pragma unroll
    for (int mi = 0; mi < 2; ++mi)
#pragma unroll
      for (int r = 0; r < 4; ++r) {
        const int grow = m0 + wr * 32 + mi * 16 + lg * 4 + r;
        out[(size_t)grow * 1024 + gcol] = acc[mi][ni][r] + bias;
      }
  }
}

// ---------------- flash attention (causal): r18 proven body (256 blocks, 2 halves) -
__global__ __launch_bounds__(1024, 4) void k_flash(const u16* __restrict__ Q,
                                                   const u16* __restrict__ K,
                                                   const u16* __restrict__ Vt,
                                                   u16* __restrict__ Y) {
  __shared__ u16 SM[2 * 9216 + 2 * 8704];  // 71,680 B
  u16* KsB = SM;                           // [2][128*72]
  u16* VsB = SM + 2 * 9216;                // [2][64*136]
  float* Ms = (float*)SM;                  // merge alias (post-loop)

  const int t = threadIdx.x, l = t & 63, w = t >> 6;
  const int ql = l & 31, hi = l >> 5;
  const int wq = w & 3, wk = w >> 2;
  const int bid = blockIdx.x;
  const int bh = (bid & 7) + 8 * ((bid >> 3) & 3);  // 4 bh per XCD
  const int p = bid >> 5;                           // pair index 0..7
  const size_t base = (size_t)bh * 131072;
  const int b = bh >> 4, hh = bh & 15;
  const int srow = t >> 3, scol = t & 7;  // K tile: 128 rows x 8 granules
  const int sd = t >> 4, sck = t & 15;    // V tile: 64 d-rows x 16 key-granules

  for (int half = 0; half < 2; ++half) {
    const int qt = half ? 15 - p : p;  // 128-row q-tile index (0..15)
    const int nsteps = qt + 1;         // 128-key kv tiles
    const int qbase = qt * 128 + wq * 32;
    const int qrow = qbase + ql;

    __syncthreads();  // previous half's merge reads done (LDS reuse)

    bf16x8 qb[4];
#pragma unroll
    for (int m = 0; m < 4; ++m)
      qb[m] = *(const bf16x8*)(Q + base + (size_t)qrow * 64 + hi * 8 + 16 * m);

    {
      ushort8 kv = *(const ushort8*)(K + base + (size_t)srow * 64 + scol * 8);
      ushort8 vv = *(const ushort8*)(Vt + base + (size_t)sd * 2048 + sck * 8);
      *(ushort8*)(KsB + srow * 72 + scol * 8) = kv;
      *(ushort8*)(VsB + sd * 136 + sck * 8) = vv;
    }
    __syncthreads();

    f32x16 accO0 = {}, accO1 = {};  // O^T: q=ql, d=(r&3)+8*(r>>2)+4*hi (+32)
    float rs_lane = 0.f;
    const int krow = wk * 32 + ql;

    for (int n = 0; n < nsteps; ++n) {
      const u16* Kc = KsB + (n & 1) * 9216;
      const u16* Vc = VsB + (n & 1) * 8704;
      const bool more = (n + 1 < nsteps);
      ushort8 kv, vv;
      if (more) {  // issue next-tile loads early; land under compute
        kv = *(const ushort8*)(K + base + (size_t)((n + 1) * 128 + srow) * 64 + scol * 8);
        vv = *(const ushort8*)(Vt + base + (size_t)sd * 2048 + (n + 1) * 128 + sck * 8);
      }
      const int kbase = n * 128 + wk * 32;
      if (kbase <= qbase + 31) {  // else fully masked for this wave
        f32x16 st = {};
        __builtin_amdgcn_s_setprio(1);
#pragma unroll
        for (int m = 0; m < 4; ++m) {
          bf16x8 ka = *(const bf16x8*)(Kc + krow * 72 + (hi + 2 * m) * 8);
          st = mfma32(ka, qb[m], st);
        }
        __builtin_amdgcn_s_setprio(0);
        if (kbase + 31 > qbase) {  // diagonal: causal mask
#pragma unroll
          for (int r = 0; r < 16; ++r) {
            const int keyl = (r & 3) + 8 * (r >> 2) + 4 * hi;
            if (kbase + keyl > qrow) st[r] = -1e30f;
          }
        }
        float pp[16];
#pragma unroll
        for (int r = 0; r < 16; ++r) {
          pp[r] = EXP2(st[r]);
          rs_lane += pp[r];
        }
        unsigned uu[8];
#pragma unroll
        for (int i = 0; i < 8; ++i) uu[i] = cvtpk(pp[2 * i], pp[2 * i + 1]);
        plswap(uu[0], uu[2]);
        plswap(uu[1], uu[3]);
        plswap(uu[4], uu[6]);
        plswap(uu[5], uu[7]);
        uint4v w0 = {uu[0], uu[1], uu[2], uu[3]};
        uint4v w1 = {uu[4], uu[5], uu[6], uu[7]};
        bf16x8 pf0 = __builtin_bit_cast(bf16x8, w0);
        bf16x8 pf1 = __builtin_bit_cast(bf16x8, w1);
        __builtin_amdgcn_s_setprio(1);
        {
          bf16x8 va0 = *(const bf16x8*)(Vc + ql * 136 + (4 * wk + hi) * 8);
          bf16x8 va1 = *(const bf16x8*)(Vc + ql * 136 + (4 * wk + 2 + hi) * 8);
          accO0 = mfma32(va0, pf0, accO0);
          accO0 = mfma32(va1, pf1, accO0);
          bf16x8 vb0 = *(const bf16x8*)(Vc + (32 + ql) * 136 + (4 * wk + hi) * 8);
          bf16x8 vb1 = *(const bf16x8*)(Vc + (32 + ql) * 136 + (4 * wk + 2 + hi) * 8);
          accO1 = mfma32(vb0, pf0, accO1);
          accO1 = mfma32(vb1, pf1, accO1);
        }
        __builtin_amdgcn_s_setprio(0);
      }
      if (more) {  // write next tile (compiler inserts vmcnt for kv/vv)
        u16* Kn = KsB + ((n + 1) & 1) * 9216;
        u16* Vn = VsB + ((n + 1) & 1) * 8704;
        *(ushort8*)(Kn + srow * 72 + scol * 8) = kv;
        *(ushort8*)(Vn + sd * 136 + sck * 8) = vv;
      }
      __syncthreads();  // writes visible; everyone done reading buf[n&1]
    }

    rs_lane += __shfl_xor(rs_lane, 32);

    // hierarchical 4-way wk merge (Ms aliases dead K/V buffers)
    {
      float* Mp = Ms + (size_t)(((wq * 2 + (wk >> 1)) * 64 + l)) * 33;
      if (wk & 1) {
#pragma unroll
        for (int i = 0; i < 16; ++i) Mp[i] = accO0[i];
#pragma unroll
        for (int i = 0; i < 16; ++i) Mp[16 + i] = accO1[i];
        Mp[32] = rs_lane;
      }
      __syncthreads();
      if (!(wk & 1)) {
#pragma unroll
        for (int i = 0; i < 16; ++i) accO0[i] += Mp[i];
#pragma unroll
        for (int i = 0; i < 16; ++i) accO1[i] += Mp[16 + i];
        rs_lane += Mp[32];
      }
      __syncthreads();
    }
    {
      float* Mp = Ms + (size_t)((wq * 64 + l)) * 33;
      if (wk == 2) {
#pragma unroll
        for (int i = 0; i < 16; ++i) Mp[i] = accO0[i];
#pragma unroll
        for (int i = 0; i < 16; ++i) Mp[16 + i] = accO1[i];
        Mp[32] = rs_lane;
      }
      __syncthreads();
      if (wk == 0) {
        const float inv = 1.0f / (rs_lane + Mp[32]);
        u16* yb = Y + ((size_t)(b * 2048 + qrow)) * 1024 + hh * 64;
#pragma unroll
        for (int rq = 0; rq < 4; ++rq) {
          const int d0 = 8 * rq + 4 * hi;
          ushort4 o4;
          o4.x = f2bf((accO0[rq * 4 + 0] + Mp[rq * 4 + 0]) * inv);
          o4.y = f2bf((accO0[rq * 4 + 1] + Mp[rq * 4 + 1]) * inv);
          o4.z = f2bf((accO0[rq * 4 + 2] + Mp[rq * 4 + 2]) * inv);
          o4.w = f2bf((accO0[rq * 4 + 3] + Mp[rq * 4 + 3]) * inv);
          *(ushort4*)(yb + d0) = o4;
        }
#pragma unroll
        for (int rq = 0; rq < 4; ++rq) {
          const int d0 = 32 + 8 * rq + 4 * hi;
          ushort4 o4;
          o4.x = f2bf((accO1[rq * 4 + 0] + Mp[16 + rq * 4 + 0]) * inv);
          o4.y = f2bf((accO1[rq * 4 + 1] + Mp[16 + rq * 4 + 1]) * inv);
          o4.z = f2bf((accO1[rq * 4 + 2] + Mp[16 + rq * 4 + 2]) * inv);
          o4.w = f2bf((accO1[rq * 4 + 3] + Mp[16 + rq * 4 + 3]) * inv);
          *(ushort4*)(yb + d0) = o4;
        }
      }
    }
  }
}

// ---------------- launch ----------------
extern "C" void kernel_launch(void* const* d_in, const int* in_sizes, int n_in,
                              void* d_out, int out_size, void* d_ws, size_t ws_size,
                              hipStream_t stream) {
  const float* x      = (const float*)d_in[0];
  const float* W_attn = (const float*)d_in[1];
  const float* b_attn = (const float*)d_in[2];
  const float* W_proj = (const float*)d_in[3];
  const float* b_proj = (const float*)d_in[4];
  float* out = (float*)d_out;

  char* ws = (char*)d_ws;              // 48 MB total
  u16* xb  = (u16*)(ws);               //  8 MB  x as bf16
  u16* WaT = (u16*)(ws + (8u  << 20)); //  6 MB  W_attn^T bf16
  u16* WpT = (u16*)(ws + (14u << 20)); //  2 MB  W_proj^T bf16
  u16* Qb  = (u16*)(ws + (16u << 20)); //  8 MB  [B*H][T][D]  (pre-scaled)
  u16* Kb  = (u16*)(ws + (24u << 20)); //  8 MB
  u16* Vtb = (u16*)(ws + (32u << 20)); //  8 MB  V^T [B*H][D][T] (written by qkv)
  u16* Yb  = (u16*)(ws + (40u << 20)); //  8 MB  attn out bf16

  k_prep<<<dim3(6144), dim3(256), 0, stream>>>(x, xb, W_attn, WaT, W_proj, WpT);
  k_gemm_qkv<<<dim3(768), dim3(256), 0, stream>>>(xb, WaT, b_attn, Qb, Kb, Vtb);
  k_flash<<<dim3(256), dim3(1024), 0, stream>>>(Qb, Kb, Vtb, Yb);
  k_gemm_proj<<<dim3(8, 64), dim3(256), 0, stream>>>(Yb, WpT, b_proj, out);
}